// Round 1
// baseline (60324.902 us; speedup 1.0000x reference)
//
#include <hip/hip_runtime.h>
#include <hip/hip_bf16.h>
#include <math.h>

#define HIDDEN 512
#define EN 256
#define ET 512
#define VOCAB_N 300
#define VOCAB_T 10000
#define ATTN 50
#define V_OUT (VOCAB_T + ATTN + 3)   // 10053
#define EOF_N (VOCAB_N - 1)          // 299
#define EOF_T (VOCAB_T - 1)          // 9999
#define SOS 0
#define CONF 0.9f
#define SM_VAL (0.1f / (float)(V_OUT - 2))
#define BB 32
#define LL 128

__device__ __forceinline__ float wave_red(float v) {
    for (int o = 32; o > 0; o >>= 1) v += __shfl_down(v, o);
    return v;
}

__global__ void k_zero(float* p, int n) {
    int i = blockIdx.x * 256 + threadIdx.x;
    int stride = gridDim.x * 256;
    for (; i < n; i += stride) p[i] = 0.0f;
}

// gates[b][g] = x @ w_ih^T + b_ih + h @ w_hh^T + b_hh ; one wave per (b,g)
__global__ void k_gates(const float* __restrict__ embN, const float* __restrict__ embT,
                        const float* __restrict__ w_ih, const float* __restrict__ w_hh,
                        const float* __restrict__ b_ih, const float* __restrict__ b_hh,
                        const int* __restrict__ n_t, const int* __restrict__ t_t,
                        const float* __restrict__ h, float* __restrict__ gates, int it) {
    int wid = blockIdx.x * 4 + (threadIdx.x >> 6);
    int lane = threadIdx.x & 63;
    int b = wid >> 11;         // 2048 gates per batch row
    int g = wid & 2047;
    int in_n = (it == 0) ? SOS : n_t[b * LL + it - 1];
    int in_t = (it == 0) ? SOS : t_t[b * LL + it - 1];
    const float* wr = w_ih + (size_t)g * (EN + ET);
    const float* eN = embN + (size_t)in_n * EN;
    const float* eT = embT + (size_t)in_t * ET;
    const float* wh = w_hh + (size_t)g * HIDDEN;
    const float* hb = h + b * HIDDEN;
    float acc = 0.0f;
    for (int k = lane; k < EN; k += 64) acc += eN[k] * wr[k];
    for (int k = lane; k < ET; k += 64) acc += eT[k] * wr[EN + k];
    for (int k = lane; k < HIDDEN; k += 64) acc += hb[k] * wh[k];
    acc = wave_red(acc);
    if (lane == 0) gates[b * 2048 + g] = acc + b_ih[g] + b_hh[g];
}

// LSTM pointwise: c,h update (in place)
__global__ void k_cell(const float* __restrict__ gates, float* __restrict__ h, float* __restrict__ c) {
    int idx = blockIdx.x * 256 + threadIdx.x;   // 0..16383
    int b = idx >> 9, j = idx & 511;
    const float* gb = gates + b * 2048;
    float ig = gb[j], fg = gb[512 + j], gg = gb[1024 + j], og = gb[1536 + j];
    float si = 1.0f / (1.0f + expf(-ig));
    float sf = 1.0f / (1.0f + expf(-fg));
    float so = 1.0f / (1.0f + expf(-og));
    float cn = sf * c[idx] + si * tanhf(gg);
    c[idx] = cn;
    h[idx] = so * tanhf(cn);
}

// per-batch-row: hc_parent snapshot, hs write, attention, s_t
__global__ void k_attn(const float* __restrict__ Wh_w, const float* __restrict__ Wh_b,
                       const float* __restrict__ v_w, const float* __restrict__ v_b,
                       const float* __restrict__ Ws_w, const float* __restrict__ Ws_b,
                       const int* __restrict__ n_t, const int* __restrict__ p_t,
                       const float* __restrict__ h, const float* __restrict__ c,
                       float* __restrict__ hs, float* __restrict__ hcp,
                       float* __restrict__ attn, float* __restrict__ s_t, int it) {
    __shared__ float h_s[512];
    __shared__ float a_s[512];
    __shared__ float sc[64];
    __shared__ float rbuf[256];
    int b = blockIdx.x;
    int tid = threadIdx.x;
    int lane = tid & 63, wv = tid >> 6;
    int parent = (it == 0) ? 0 : p_t[b * LL + it - 1];
    // hc_parent BEFORE hs[:,it] write (parent==it must see zeros, as in the reference)
    for (int k = tid; k < 512; k += 256) hcp[b * 512 + k] = hs[((size_t)b * LL + parent) * 512 + k];
    for (int k = tid; k < 512; k += 256) h_s[k] = h[b * 512 + k];
    __syncthreads();
    for (int k = tid; k < 512; k += 256) hs[((size_t)b * LL + it) * 512 + k] = h_s[k];
    // a = h @ Wh^T + Wh_b (wave per row for coalesced weight reads)
    for (int j = wv; j < 512; j += 4) {
        const float* wr = Wh_w + (size_t)j * 512;
        float acc = 0.0f;
        for (int k = lane; k < 512; k += 64) acc += h_s[k] * wr[k];
        acc = wave_red(acc);
        if (lane == 0) a_s[j] = acc + Wh_b[j];
    }
    __syncthreads();
    // 50 scores, wave per window slot
    for (int w = wv; w < ATTN; w += 4) {
        int idx = it + w - ATTN;            // in [it-50, it-1]
        int idxc = idx < 0 ? 0 : idx;
        bool mask = (idx < 0) || (n_t[b * LL + idxc] == EOF_N);
        float s;
        if (mask) {
            s = -1e20f;
        } else {
            const float* mrow = hs + ((size_t)b * LL + idxc) * 512;
            float acc = 0.0f;
            for (int k = lane; k < 512; k += 64) acc += v_w[k] * tanhf(a_s[k] + mrow[k]);
            acc = wave_red(acc);
            s = acc + v_b[0];
        }
        if (lane == 0) sc[w] = s;
    }
    __syncthreads();
    if (tid == 0) {
        float m = -INFINITY;
        for (int w = 0; w < ATTN; w++) m = fmaxf(m, sc[w]);
        float Z = 0.0f;
        for (int w = 0; w < ATTN; w++) { sc[w] = expf(sc[w] - m); Z += sc[w]; }
        for (int w = 0; w < ATTN; w++) attn[b * ATTN + w] = sc[w] / Z;
    }
    // s_t = sigmoid([h,c] @ Ws^T + Ws_b)
    {
        float acc = 0.0f;
        for (int k = tid; k < 512; k += 256) acc += h_s[k] * Ws_w[k];
        for (int k = tid; k < 512; k += 256) acc += c[b * 512 + k] * Ws_w[512 + k];
        rbuf[tid] = acc;
        __syncthreads();
        for (int s2 = 128; s2 > 0; s2 >>= 1) {
            if (tid < s2) rbuf[tid] += rbuf[tid + s2];
            __syncthreads();
        }
        if (tid == 0) s_t[b] = 1.0f / (1.0f + expf(-(rbuf[0] + Ws_b[0])));
    }
}

// logits[b][j] = [h,c,hcp] @ Wg_w[j] + Wg_b[j] ; one wave per j, blockIdx.y = b
__global__ void k_logits(const float* __restrict__ Wg_w, const float* __restrict__ Wg_b,
                         const float* __restrict__ h, const float* __restrict__ c,
                         const float* __restrict__ hcp, float* __restrict__ logits) {
    int b = blockIdx.y;
    int j = blockIdx.x * 4 + (threadIdx.x >> 6);
    if (j >= V_OUT) return;
    int lane = threadIdx.x & 63;
    const float* wr = Wg_w + (size_t)j * 1536;
    const float* hb = h + b * 512;
    const float* cb = c + b * 512;
    const float* pb = hcp + b * 512;
    float acc = 0.0f;
    for (int k = lane; k < 512; k += 64) {
        acc += hb[k] * wr[k];
        acc += cb[k] * wr[512 + k];
        acc += pb[k] * wr[1024 + k];
    }
    acc = wave_red(acc);
    if (lane == 0) logits[(size_t)b * V_OUT + j] = acc + Wg_b[j];
}

// per-batch-row: log_softmax stats, mixture cond, argmax, loss
__global__ void k_final(const float* __restrict__ logits, const float* __restrict__ attn,
                        const float* __restrict__ s_tp, const int* __restrict__ t_t,
                        float* __restrict__ tl_partial, float* __restrict__ out, int it) {
    __shared__ float mv[256];
    __shared__ int mi[256];
    __shared__ float sv[256];
    int b = blockIdx.x, tid = threadIdx.x;
    const float* lg = logits + (size_t)b * V_OUT;
    float lmax = -INFINITY; int limax = 0; float lsum = 0.0f;
    for (int j = tid; j < V_OUT; j += 256) {
        float v = lg[j];
        lsum += v;
        if (v > lmax) { lmax = v; limax = j; }
    }
    mv[tid] = lmax; mi[tid] = limax; sv[tid] = lsum;
    __syncthreads();
    for (int s2 = 128; s2 > 0; s2 >>= 1) {
        if (tid < s2) {
            if (mv[tid + s2] > mv[tid] || (mv[tid + s2] == mv[tid] && mi[tid + s2] < mi[tid])) {
                mv[tid] = mv[tid + s2]; mi[tid] = mi[tid + s2];
            }
            sv[tid] += sv[tid + s2];
        }
        __syncthreads();
    }
    float M = mv[0]; int argJ = mi[0]; float sumL = sv[0];
    __syncthreads();
    float esum = 0.0f;
    for (int j = tid; j < V_OUT; j += 256) esum += expf(lg[j] - M);
    sv[tid] = esum;
    __syncthreads();
    for (int s2 = 128; s2 > 0; s2 >>= 1) {
        if (tid < s2) sv[tid] += sv[tid + s2];
        __syncthreads();
    }
    if (tid == 0) {
        float lse = logf(sv[0]);
        float st = s_tp[b];
        float amax = -INFINITY; int aarg = 0; float asum = 0.0f;
        for (int w = 0; w < ATTN; w++) {
            float v = attn[b * ATTN + w];
            asum += v;
            if (v > amax) { amax = v; aarg = w; }
        }
        float max_out = st * (-lse);               // s_t * max(log_softmax)
        float max_loc = (1.0f - st) * amax;
        bool cond = max_out > max_loc;             // provably ~always false; kept for fidelity
        int t_col = t_t[b * LL + it];
        const float CONST_T = CONF * logf(CONF) + 0.1f * logf(SM_VAL);
        float tl; int topi;
        if (!cond) {
            topi = argJ;
            float off = M + lse;
            float out_t = st * (lg[t_col] - off);
            float out_e = st * (lg[EOF_T] - off);
            float S = st * (sumL - (float)V_OUT * off);
            tl = CONST_T - (SM_VAL * (S - out_e - out_t) + CONF * out_t);
        } else {
            float pmax = (1.0f - st) * amax;
            topi = (pmax > 0.0f) ? (VOCAB_T + aarg) : 0;
            float S = (1.0f - st) * asum;
            tl = CONST_T - SM_VAL * S;
        }
        if (t_col == EOF_T) tl = 0.0f;
        tl_partial[it * BB + b] = tl;
        out[1 + b * LL + it] = (float)topi;
    }
}

__global__ void k_sumloss(const float* __restrict__ tl_partial, float* __restrict__ out) {
    __shared__ float r[256];
    float a = 0.0f;
    for (int i = threadIdx.x; i < BB * LL; i += 256) a += tl_partial[i];
    r[threadIdx.x] = a;
    __syncthreads();
    for (int s = 128; s > 0; s >>= 1) {
        if (threadIdx.x < s) r[threadIdx.x] += r[threadIdx.x + s];
        __syncthreads();
    }
    if (threadIdx.x == 0) out[0] = r[0];
}

extern "C" void kernel_launch(void* const* d_in, const int* in_sizes, int n_in,
                              void* d_out, int out_size, void* d_ws, size_t ws_size,
                              hipStream_t stream) {
    const int*   n_t  = (const int*)d_in[0];
    const int*   t_t  = (const int*)d_in[1];
    const int*   p_t  = (const int*)d_in[2];
    const float* embN = (const float*)d_in[3];
    const float* embT = (const float*)d_in[4];
    const float* w_ih = (const float*)d_in[5];
    const float* w_hh = (const float*)d_in[6];
    const float* b_ih = (const float*)d_in[7];
    const float* b_hh = (const float*)d_in[8];
    const float* Wh_w = (const float*)d_in[9];
    const float* Wh_b = (const float*)d_in[10];
    const float* v_w  = (const float*)d_in[11];
    const float* v_b  = (const float*)d_in[12];
    const float* Wg_w = (const float*)d_in[13];
    const float* Wg_b = (const float*)d_in[14];
    const float* Ws_w = (const float*)d_in[15];
    const float* Ws_b = (const float*)d_in[16];
    float* out = (float*)d_out;

    // workspace layout (floats)
    float* ws = (float*)d_ws;
    float* hs         = ws;                       // 32*128*512 = 2097152
    float* h          = hs + 2097152;             // 16384
    float* c          = h + 16384;                // 16384
    float* gates      = c + 16384;                // 65536
    float* hcp        = gates + 65536;            // 16384
    float* attn       = hcp + 16384;              // 1600
    float* s_t        = attn + 1600;              // 32
    float* logits     = s_t + 32;                 // 32*10053 = 321696
    float* tl_partial = logits + 321696;          // 4096

    // zero hs, h, c (ws is poisoned with 0xAA before every timed launch)
    k_zero<<<2048, 256, 0, stream>>>(hs, 2097152 + 16384 + 16384);

    const int LOGIT_BX = (V_OUT + 3) / 4;  // 2514 blocks of 4 waves
    for (int it = 0; it < LL; ++it) {
        k_gates<<<16384, 256, 0, stream>>>(embN, embT, w_ih, w_hh, b_ih, b_hh, n_t, t_t, h, gates, it);
        k_cell<<<64, 256, 0, stream>>>(gates, h, c);
        k_attn<<<32, 256, 0, stream>>>(Wh_w, Wh_b, v_w, v_b, Ws_w, Ws_b, n_t, p_t,
                                       h, c, hs, hcp, attn, s_t, it);
        k_logits<<<dim3(LOGIT_BX, 32), 256, 0, stream>>>(Wg_w, Wg_b, h, c, hcp, logits);
        k_final<<<32, 256, 0, stream>>>(logits, attn, s_t, t_t, tl_partial, out, it);
    }
    k_sumloss<<<1, 256, 0, stream>>>(tl_partial, out);
}

// Round 2
// 23219.972 us; speedup vs baseline: 2.5980x; 2.5980x over previous
//
#include <hip/hip_runtime.h>
#include <hip/hip_bf16.h>
#include <math.h>

#define HIDDEN 512
#define EN 256
#define ET 512
#define VOCAB_N 300
#define VOCAB_T 10000
#define ATTN 50
#define V_OUT (VOCAB_T + ATTN + 3)   // 10053
#define EOF_N (VOCAB_N - 1)          // 299
#define EOF_T (VOCAB_T - 1)          // 9999
#define SOS 0
#define CONF 0.9f
#define SM_VAL (0.1f / (float)(V_OUT - 2))
#define BB 32
#define LL 128

#define KTOT_G 1280     // 768 (w_ih) + 512 (w_hh)
#define KTOT_L 1536     // h, c, hcp
#define GS 4            // split-K factor (both GEMMs)

__global__ void k_zero(float* p, int n) {
    int i = blockIdx.x * 256 + threadIdx.x;
    int stride = gridDim.x * 256;
    for (; i < n; i += stride) p[i] = 0.0f;
}

// WhT[k][j] = Wh_w[j][k] — once per launch
__global__ void k_trans(const float* __restrict__ Wh_w, float* __restrict__ WhT) {
    int k = blockIdx.x;
    for (int j = threadIdx.x; j < 512; j += 256)
        WhT[k * 512 + j] = Wh_w[j * 512 + k];
}

// ---------------- gates GEMM: gpart[s][b][2048] = X[32,1280] @ W^T (split-K) ----
// X[b] = [embN[in_n[b]] (256) | embT[in_t[b]] (512) | h[b] (512)]
// W row j = [w_ih[j] (768) | w_hh[j] (512)]
// BN=64, BK=64, grid (32, 4), 256 thr, acc 4b x 2j
__global__ __launch_bounds__(256) void k_gates(
        const float* __restrict__ embN, const float* __restrict__ embT,
        const float* __restrict__ w_ih, const float* __restrict__ w_hh,
        const int* __restrict__ n_t, const int* __restrict__ t_t,
        const float* __restrict__ h, float* __restrict__ gpart, int it) {
    __shared__ float Ws[64][64];
    __shared__ float Xs[64][32];
    int jt = blockIdx.x * 64;
    int s  = blockIdx.y;
    int tid = threadIdx.x;
    int jq = tid & 31;          // j0 = jq*2
    int bq = tid >> 5;          // b0 = bq*4
    float acc[4][2] = {{0.f,0.f},{0.f,0.f},{0.f,0.f},{0.f,0.f}};

    // X-gather indices for this thread's staging row
    int xb = tid >> 3;                    // 0..31
    int xk = (tid & 7) * 8;               // 0..56
    int in_n = (it == 0) ? SOS : n_t[xb * LL + it - 1];
    int in_t = (it == 0) ? SOS : t_t[xb * LL + it - 1];

    const int kbase = s * (KTOT_G / GS);  // s*320
    for (int ch = 0; ch < (KTOT_G / GS) / 64; ++ch) {   // 5 chunks
        int k0 = kbase + ch * 64;
        // ---- stage W (transpose to k-major): thread -> row jr, 16 k
        {
            int jr = tid >> 2;              // 0..63
            int kh = (tid & 3) * 16;
            int jg = jt + jr;
            #pragma unroll
            for (int i = 0; i < 4; ++i) {
                int kg = k0 + kh + i * 4;
                float4 v;
                if (kg < 768) v = *(const float4*)(w_ih + (size_t)jg * 768 + kg);
                else          v = *(const float4*)(w_hh + (size_t)jg * 512 + (kg - 768));
                int kk = kh + i * 4;
                Ws[kk][jr] = v.x; Ws[kk+1][jr] = v.y; Ws[kk+2][jr] = v.z; Ws[kk+3][jr] = v.w;
            }
        }
        // ---- stage X (gathered)
        {
            #pragma unroll
            for (int i = 0; i < 2; ++i) {
                int kg = k0 + xk + i * 4;
                float4 v;
                if (kg < 256)      v = *(const float4*)(embN + (size_t)in_n * EN + kg);
                else if (kg < 768) v = *(const float4*)(embT + (size_t)in_t * ET + (kg - 256));
                else               v = *(const float4*)(h + xb * 512 + (kg - 768));
                int kk = xk + i * 4;
                Xs[kk][xb] = v.x; Xs[kk+1][xb] = v.y; Xs[kk+2][xb] = v.z; Xs[kk+3][xb] = v.w;
            }
        }
        __syncthreads();
        #pragma unroll 8
        for (int kk = 0; kk < 64; ++kk) {
            float4 xv = *(const float4*)&Xs[kk][bq * 4];
            float2 wv = *(const float2*)&Ws[kk][jq * 2];
            acc[0][0] += xv.x * wv.x; acc[0][1] += xv.x * wv.y;
            acc[1][0] += xv.y * wv.x; acc[1][1] += xv.y * wv.y;
            acc[2][0] += xv.z * wv.x; acc[2][1] += xv.z * wv.y;
            acc[3][0] += xv.w * wv.x; acc[3][1] += xv.w * wv.y;
        }
        __syncthreads();
    }
    float* gp = gpart + (size_t)s * (BB * 2048);
    #pragma unroll
    for (int r = 0; r < 4; ++r)
        #pragma unroll
        for (int q = 0; q < 2; ++q)
            gp[(bq * 4 + r) * 2048 + jt + jq * 2 + q] = acc[r][q];
}

// ---------------- fused cell + attention, one block per b -------------------
__global__ __launch_bounds__(256) void k_attn(
        const float* __restrict__ gpart,
        const float* __restrict__ b_ih, const float* __restrict__ b_hh,
        const float* __restrict__ WhT, const float* __restrict__ Wh_b,
        const float* __restrict__ v_w, const float* __restrict__ v_b,
        const float* __restrict__ Ws_w, const float* __restrict__ Ws_b,
        const int* __restrict__ n_t, const int* __restrict__ p_t,
        float* __restrict__ h, float* __restrict__ c,
        float* __restrict__ hs, float* __restrict__ hcp,
        float* __restrict__ attn, float* __restrict__ s_t, int it) {
    __shared__ float h_s[512];
    __shared__ float c_s[512];
    __shared__ float a_s[512];
    __shared__ float sc[64];
    __shared__ float red[256];
    int b = blockIdx.x;
    int tid = threadIdx.x;
    int lane = tid & 63, wv = tid >> 6;

    // phase 0: hc_parent snapshot BEFORE hs[:,it] write (parent==it must see old/zero)
    int parent = (it == 0) ? 0 : p_t[b * LL + it - 1];
    for (int k = tid; k < 512; k += 256)
        hcp[b * 512 + k] = hs[((size_t)b * LL + parent) * 512 + k];
    __syncthreads();

    // phase 1: sum split-K partials, LSTM cell
    for (int j = tid; j < 512; j += 256) {
        float ig = b_ih[j] + b_hh[j];
        float fg = b_ih[512 + j] + b_hh[512 + j];
        float gg = b_ih[1024 + j] + b_hh[1024 + j];
        float og = b_ih[1536 + j] + b_hh[1536 + j];
        #pragma unroll
        for (int s = 0; s < GS; ++s) {
            const float* gp = gpart + (size_t)s * (BB * 2048) + b * 2048;
            ig += gp[j]; fg += gp[512 + j]; gg += gp[1024 + j]; og += gp[1536 + j];
        }
        float si = 1.0f / (1.0f + expf(-ig));
        float sf = 1.0f / (1.0f + expf(-fg));
        float so = 1.0f / (1.0f + expf(-og));
        float cn = sf * c[b * 512 + j] + si * tanhf(gg);
        float hn = so * tanhf(cn);
        c_s[j] = cn; h_s[j] = hn;
        c[b * 512 + j] = cn; h[b * 512 + j] = hn;
        hs[((size_t)b * LL + it) * 512 + j] = hn;
    }
    __syncthreads();

    // phase 2: a = h @ Wh^T + Wh_b via transposed weights (thread-per-2-columns)
    {
        int j0 = tid * 2;
        float ax = 0.f, ay = 0.f;
        const float2* wp = (const float2*)WhT + (j0 >> 1);   // stride 256 float2 per k
        #pragma unroll 4
        for (int k = 0; k < 512; ++k) {
            float hk = h_s[k];
            float2 w = wp[k * 256];
            ax += hk * w.x; ay += hk * w.y;
        }
        a_s[j0] = ax + Wh_b[j0];
        a_s[j0 + 1] = ay + Wh_b[j0 + 1];
    }
    __syncthreads();

    // phase 3: 50 attention scores, wave per window slot
    for (int w = wv; w < ATTN; w += 4) {
        int idx = it + w - ATTN;
        int idxc = idx < 0 ? 0 : idx;
        bool mask = (idx < 0) || (n_t[b * LL + idxc] == EOF_N);
        float sres;
        if (mask) {
            sres = -1e20f;
        } else {
            const float* mrow = hs + ((size_t)b * LL + idxc) * 512;
            float acc = 0.0f;
            for (int k = lane; k < 512; k += 64) acc += v_w[k] * tanhf(a_s[k] + mrow[k]);
            for (int o = 32; o > 0; o >>= 1) acc += __shfl_down(acc, o);
            sres = acc + v_b[0];
        }
        if (lane == 0) sc[w] = sres;
    }
    __syncthreads();
    if (tid == 0) {
        float m = -INFINITY;
        for (int w = 0; w < ATTN; w++) m = fmaxf(m, sc[w]);
        float Z = 0.0f;
        for (int w = 0; w < ATTN; w++) { sc[w] = expf(sc[w] - m); Z += sc[w]; }
        for (int w = 0; w < ATTN; w++) attn[b * ATTN + w] = sc[w] / Z;
    }
    // phase 4: s_t = sigmoid([h,c] @ Ws^T + Ws_b)
    {
        float acc = 0.0f;
        for (int k = tid; k < 512; k += 256) acc += h_s[k] * Ws_w[k];
        for (int k = tid; k < 512; k += 256) acc += c_s[k] * Ws_w[512 + k];
        red[tid] = acc;
        __syncthreads();
        for (int s2 = 128; s2 > 0; s2 >>= 1) {
            if (tid < s2) red[tid] += red[tid + s2];
            __syncthreads();
        }
        if (tid == 0) s_t[b] = 1.0f / (1.0f + expf(-(red[0] + Ws_b[0])));
    }
}

// ---------------- logits GEMM: lpart[s][b][V_OUT] = [h,c,hcp] @ Wg^T (split-K) --
// BN=128, BK=64, grid (79, 4), 256 thr, acc 4b x 4j
__global__ __launch_bounds__(256) void k_logits(
        const float* __restrict__ Wg_w,
        const float* __restrict__ h, const float* __restrict__ c,
        const float* __restrict__ hcp, float* __restrict__ lpart) {
    __shared__ float Ws[64][128];
    __shared__ float Xs[64][32];
    int jt = blockIdx.x * 128;
    int s  = blockIdx.y;
    int tid = threadIdx.x;
    int jq = tid & 31;          // j0 = jq*4
    int bq = tid >> 5;          // b0 = bq*4
    float acc[4][4];
    #pragma unroll
    for (int r = 0; r < 4; ++r)
        #pragma unroll
        for (int q = 0; q < 4; ++q) acc[r][q] = 0.f;

    const int kbase = s * (KTOT_L / GS);   // s*384
    for (int ch = 0; ch < (KTOT_L / GS) / 64; ++ch) {   // 6 chunks
        int k0 = kbase + ch * 64;
        // ---- stage W (transpose to k-major): thread -> row jr, 32 k
        {
            int jr = tid >> 1;               // 0..127
            int kh = (tid & 1) * 32;
            int jg = jt + jr;
            int jgc = jg < V_OUT ? jg : 0;   // clamp OOB rows (results discarded)
            const float* src = Wg_w + (size_t)jgc * KTOT_L + k0 + kh;
            #pragma unroll
            for (int i = 0; i < 8; ++i) {
                float4 v = *(const float4*)(src + i * 4);
                int kk = kh + i * 4;
                Ws[kk][jr] = v.x; Ws[kk+1][jr] = v.y; Ws[kk+2][jr] = v.z; Ws[kk+3][jr] = v.w;
            }
        }
        // ---- stage X: [h | c | hcp] per b
        {
            int xb = tid >> 3;
            int xk = (tid & 7) * 8;
            #pragma unroll
            for (int i = 0; i < 2; ++i) {
                int kg = k0 + xk + i * 4;
                const float* src;
                if (kg < 512)       src = h   + xb * 512 + kg;
                else if (kg < 1024) src = c   + xb * 512 + (kg - 512);
                else                src = hcp + xb * 512 + (kg - 1024);
                float4 v = *(const float4*)src;
                int kk = xk + i * 4;
                Xs[kk][xb] = v.x; Xs[kk+1][xb] = v.y; Xs[kk+2][xb] = v.z; Xs[kk+3][xb] = v.w;
            }
        }
        __syncthreads();
        #pragma unroll 8
        for (int kk = 0; kk < 64; ++kk) {
            float4 xv = *(const float4*)&Xs[kk][bq * 4];
            float4 wv = *(const float4*)&Ws[kk][jq * 4];
            acc[0][0] += xv.x * wv.x; acc[0][1] += xv.x * wv.y; acc[0][2] += xv.x * wv.z; acc[0][3] += xv.x * wv.w;
            acc[1][0] += xv.y * wv.x; acc[1][1] += xv.y * wv.y; acc[1][2] += xv.y * wv.z; acc[1][3] += xv.y * wv.w;
            acc[2][0] += xv.z * wv.x; acc[2][1] += xv.z * wv.y; acc[2][2] += xv.z * wv.z; acc[2][3] += xv.z * wv.w;
            acc[3][0] += xv.w * wv.x; acc[3][1] += xv.w * wv.y; acc[3][2] += xv.w * wv.z; acc[3][3] += xv.w * wv.w;
        }
        __syncthreads();
    }
    float* lp = lpart + (size_t)s * (BB * V_OUT);
    #pragma unroll
    for (int r = 0; r < 4; ++r)
        #pragma unroll
        for (int q = 0; q < 4; ++q) {
            int jg = jt + jq * 4 + q;
            if (jg < V_OUT) lp[(size_t)(bq * 4 + r) * V_OUT + jg] = acc[r][q];
        }
}

// ---------------- per-b finalize: logsoftmax stats, mixture, argmax, loss ------
__global__ __launch_bounds__(256) void k_final(
        const float* __restrict__ lpart, const float* __restrict__ Wg_b,
        float* __restrict__ logits,
        const float* __restrict__ attn, const float* __restrict__ s_tp,
        const int* __restrict__ t_t,
        float* __restrict__ tl_partial, float* __restrict__ out, int it) {
    __shared__ float mv[256];
    __shared__ int mi[256];
    __shared__ float sv[256];
    int b = blockIdx.x, tid = threadIdx.x;
    float* lg = logits + (size_t)b * V_OUT;
    float lmax = -INFINITY; int limax = 0; float lsum = 0.0f;
    for (int j = tid; j < V_OUT; j += 256) {
        float v = Wg_b[j];
        #pragma unroll
        for (int s = 0; s < GS; ++s) v += lpart[(size_t)s * (BB * V_OUT) + (size_t)b * V_OUT + j];
        lg[j] = v;
        lsum += v;
        if (v > lmax) { lmax = v; limax = j; }
    }
    mv[tid] = lmax; mi[tid] = limax; sv[tid] = lsum;
    __syncthreads();
    for (int s2 = 128; s2 > 0; s2 >>= 1) {
        if (tid < s2) {
            if (mv[tid + s2] > mv[tid] || (mv[tid + s2] == mv[tid] && mi[tid + s2] < mi[tid])) {
                mv[tid] = mv[tid + s2]; mi[tid] = mi[tid + s2];
            }
            sv[tid] += sv[tid + s2];
        }
        __syncthreads();
    }
    float M = mv[0]; int argJ = mi[0]; float sumL = sv[0];
    __syncthreads();
    float esum = 0.0f;
    for (int j = tid; j < V_OUT; j += 256) esum += expf(lg[j] - M);
    sv[tid] = esum;
    __syncthreads();
    for (int s2 = 128; s2 > 0; s2 >>= 1) {
        if (tid < s2) sv[tid] += sv[tid + s2];
        __syncthreads();
    }
    if (tid == 0) {
        float lse = logf(sv[0]);
        float st = s_tp[b];
        float amax = -INFINITY; int aarg = 0; float asum = 0.0f;
        for (int w = 0; w < ATTN; w++) {
            float v = attn[b * ATTN + w];
            asum += v;
            if (v > amax) { amax = v; aarg = w; }
        }
        float max_out = st * (-lse);
        float max_loc = (1.0f - st) * amax;
        bool cond = max_out > max_loc;
        int t_col = t_t[b * LL + it];
        const float CONST_T = CONF * logf(CONF) + 0.1f * logf(SM_VAL);
        float tl; int topi;
        if (!cond) {
            topi = argJ;
            float off = M + lse;
            float out_t = st * (lg[t_col] - off);
            float out_e = st * (lg[EOF_T] - off);
            float S = st * (sumL - (float)V_OUT * off);
            tl = CONST_T - (SM_VAL * (S - out_e - out_t) + CONF * out_t);
        } else {
            float pmax = (1.0f - st) * amax;
            topi = (pmax > 0.0f) ? (VOCAB_T + aarg) : 0;
            float S = (1.0f - st) * asum;
            tl = CONST_T - SM_VAL * S;
        }
        if (t_col == EOF_T) tl = 0.0f;
        tl_partial[it * BB + b] = tl;
        out[1 + b * LL + it] = (float)topi;
    }
}

__global__ void k_sumloss(const float* __restrict__ tl_partial, float* __restrict__ out) {
    __shared__ float r[256];
    float a = 0.0f;
    for (int i = threadIdx.x; i < BB * LL; i += 256) a += tl_partial[i];
    r[threadIdx.x] = a;
    __syncthreads();
    for (int s = 128; s > 0; s >>= 1) {
        if (threadIdx.x < s) r[threadIdx.x] += r[threadIdx.x + s];
        __syncthreads();
    }
    if (threadIdx.x == 0) out[0] = r[0];
}

extern "C" void kernel_launch(void* const* d_in, const int* in_sizes, int n_in,
                              void* d_out, int out_size, void* d_ws, size_t ws_size,
                              hipStream_t stream) {
    const int*   n_t  = (const int*)d_in[0];
    const int*   t_t  = (const int*)d_in[1];
    const int*   p_t  = (const int*)d_in[2];
    const float* embN = (const float*)d_in[3];
    const float* embT = (const float*)d_in[4];
    const float* w_ih = (const float*)d_in[5];
    const float* w_hh = (const float*)d_in[6];
    const float* b_ih = (const float*)d_in[7];
    const float* b_hh = (const float*)d_in[8];
    const float* Wh_w = (const float*)d_in[9];
    const float* Wh_b = (const float*)d_in[10];
    const float* v_w  = (const float*)d_in[11];
    const float* v_b  = (const float*)d_in[12];
    const float* Wg_w = (const float*)d_in[13];
    const float* Wg_b = (const float*)d_in[14];
    const float* Ws_w = (const float*)d_in[15];
    const float* Ws_b = (const float*)d_in[16];
    float* out = (float*)d_out;

    // workspace layout (floats)
    float* ws = (float*)d_ws;
    float* hs         = ws;                         // 32*128*512 = 2,097,152
    float* h          = hs + 2097152;               // 16,384
    float* c          = h + 16384;                  // 16,384
    float* gpart      = c + 16384;                  // 4*32*2048 = 262,144
    float* hcp        = gpart + 262144;             // 16,384
    float* attn       = hcp + 16384;                // 1,600
    float* s_t        = attn + 1600;                // 32
    float* lpart      = s_t + 32;                   // 4*32*10053 = 1,286,784
    float* logits     = lpart + 1286784;            // 321,696
    float* tl_partial = logits + 321696;            // 4,096
    float* WhT        = tl_partial + 4096;          // 262,144
    // total ~4.28M floats ~ 17.1 MB

    // zero hs, h, c (ws is 0xAA-poisoned before every timed launch)
    k_zero<<<2048, 256, 0, stream>>>(hs, 2097152 + 16384 + 16384);
    k_trans<<<512, 256, 0, stream>>>(Wh_w, WhT);

    for (int it = 0; it < LL; ++it) {
        k_gates<<<dim3(32, GS), 256, 0, stream>>>(embN, embT, w_ih, w_hh, n_t, t_t, h, gpart, it);
        k_attn<<<BB, 256, 0, stream>>>(gpart, b_ih, b_hh, WhT, Wh_b, v_w, v_b, Ws_w, Ws_b,
                                       n_t, p_t, h, c, hs, hcp, attn, s_t, it);
        k_logits<<<dim3(79, GS), 256, 0, stream>>>(Wg_w, h, c, hcp, lpart);
        k_final<<<BB, 256, 0, stream>>>(lpart, Wg_b, logits, attn, s_t, t_t, tl_partial, out, it);
    }
    k_sumloss<<<1, 256, 0, stream>>>(tl_partial, out);
}

// Round 3
// 14153.531 us; speedup vs baseline: 4.2622x; 1.6406x over previous
//
#include <hip/hip_runtime.h>
#include <hip/hip_bf16.h>
#include <math.h>

#define HIDDEN 512
#define EN 256
#define ET 512
#define VOCAB_N 300
#define VOCAB_T 10000
#define ATTN 50
#define V_OUT (VOCAB_T + ATTN + 3)   // 10053
#define EOF_N (VOCAB_N - 1)          // 299
#define EOF_T (VOCAB_T - 1)          // 9999
#define SOS 0
#define CONF 0.9f
#define SM_VAL (0.1f / (float)(V_OUT - 2))
#define BB 32
#define LL 128

#define GSG 8     // gates split-K (K=1280 -> 160/split, 5 chunks of 32)
#define GSL 6     // logits split-K (K=1536 -> 256/split, 8 chunks of 32)
#define JBL 40    // logits j-blocks (40*256 >= 10053)

// ---------------- init: zero hs,c; xg = [embN[SOS] | embT[SOS] | h=0] ----------
__global__ void k_init(float* __restrict__ hs, float* __restrict__ c,
                       float* __restrict__ xg,
                       const float* __restrict__ embN, const float* __restrict__ embT) {
    int i = blockIdx.x * 256 + threadIdx.x;
    int stride = gridDim.x * 256;
    for (int k = i; k < BB * LL * 512; k += stride) hs[k] = 0.0f;
    for (int k = i; k < BB * 512; k += stride) c[k] = 0.0f;
    for (int k = i; k < BB * 1280; k += stride) {
        int kk = k % 1280;
        float v;
        if (kk < 256)      v = embN[kk];          // embN[SOS]
        else if (kk < 768) v = embT[kk - 256];    // embT[SOS]
        else               v = 0.0f;              // h0
        xg[k] = v;
    }
}

// ---------------- gates GEMM: gpart[s][b][2048] = xg[32,1280] @ [w_ih|w_hh]^T --
// grid (32, GSG), 256 thr, BN=64, BK=32; thread tile 2b x 4j
__global__ __launch_bounds__(256) void k_gates(
        const float* __restrict__ w_ih, const float* __restrict__ w_hh,
        const float* __restrict__ xg, float* __restrict__ gpart) {
    __shared__ float Ws[32][64];
    __shared__ float Xs[32][32];
    int jt = blockIdx.x * 64;
    int s  = blockIdx.y;
    int tid = threadIdx.x;
    int jq = tid & 15;          // j0 = jq*4
    int bq = tid >> 4;          // b0 = bq*2
    int wjr = tid & 31, wkc = (tid >> 5) * 4;
    int xb  = tid & 31, xk  = (tid >> 5) * 4;
    float4 wreg[2], xreg;
    float acc[2][4] = {{0.f,0.f,0.f,0.f},{0.f,0.f,0.f,0.f}};
    const int kbase = s * 160;

    {   // prefetch chunk 0
        int k0 = kbase;
        int kg = k0 + wkc;
        #pragma unroll
        for (int r = 0; r < 2; ++r) {
            int row = jt + wjr + r * 32;
            wreg[r] = (kg < 768) ? *(const float4*)(w_ih + (size_t)row * 768 + kg)
                                 : *(const float4*)(w_hh + (size_t)row * 512 + (kg - 768));
        }
        xreg = *(const float4*)(xg + xb * 1280 + k0 + xk);
    }
    for (int ch = 0; ch < 5; ++ch) {
        __syncthreads();
        #pragma unroll
        for (int r = 0; r < 2; ++r) {
            Ws[wkc+0][wjr + r*32] = wreg[r].x;
            Ws[wkc+1][wjr + r*32] = wreg[r].y;
            Ws[wkc+2][wjr + r*32] = wreg[r].z;
            Ws[wkc+3][wjr + r*32] = wreg[r].w;
        }
        Xs[xk+0][xb] = xreg.x; Xs[xk+1][xb] = xreg.y;
        Xs[xk+2][xb] = xreg.z; Xs[xk+3][xb] = xreg.w;
        __syncthreads();
        if (ch < 4) {   // prefetch next chunk into regs (overlaps compute)
            int k0 = kbase + (ch + 1) * 32;
            int kg = k0 + wkc;
            #pragma unroll
            for (int r = 0; r < 2; ++r) {
                int row = jt + wjr + r * 32;
                wreg[r] = (kg < 768) ? *(const float4*)(w_ih + (size_t)row * 768 + kg)
                                     : *(const float4*)(w_hh + (size_t)row * 512 + (kg - 768));
            }
            xreg = *(const float4*)(xg + xb * 1280 + k0 + xk);
        }
        #pragma unroll 4
        for (int kk = 0; kk < 32; ++kk) {
            float4 w = *(const float4*)&Ws[kk][jq * 4];
            float2 x = *(const float2*)&Xs[kk][bq * 2];
            acc[0][0] += x.x*w.x; acc[0][1] += x.x*w.y; acc[0][2] += x.x*w.z; acc[0][3] += x.x*w.w;
            acc[1][0] += x.y*w.x; acc[1][1] += x.y*w.y; acc[1][2] += x.y*w.z; acc[1][3] += x.y*w.w;
        }
    }
    #pragma unroll
    for (int r = 0; r < 2; ++r) {
        float4 v = make_float4(acc[r][0], acc[r][1], acc[r][2], acc[r][3]);
        *(float4*)(gpart + ((size_t)s * 32 + bq * 2 + r) * 2048 + jt + jq * 4) = v;
    }
}

// ---------------- cell: partial-sum + LSTM + hs/hcp/xbuf/xg/s_t ----------------
__global__ __launch_bounds__(256) void k_cell(
        const float* __restrict__ gpart,
        const float* __restrict__ b_ih, const float* __restrict__ b_hh,
        const float* __restrict__ embN, const float* __restrict__ embT,
        const float* __restrict__ Ws_w, const float* __restrict__ Ws_b,
        const int* __restrict__ n_t, const int* __restrict__ t_t, const int* __restrict__ p_t,
        float* __restrict__ c, float* __restrict__ hs,
        float* __restrict__ xbuf, float* __restrict__ xg,
        float* __restrict__ s_t, int it) {
    __shared__ float h_s[512], c_s[512], red[256];
    int b = blockIdx.x, tid = threadIdx.x;
    // hcp snapshot BEFORE hs[:,it] write (parent==it must see pre-update value)
    int parent = (it == 0) ? 0 : p_t[b * LL + it - 1];
    for (int k = tid; k < 512; k += 256)
        xbuf[b * 1536 + 1024 + k] = hs[((size_t)b * LL + parent) * 512 + k];
    for (int jj = tid; jj < 512; jj += 256) {
        float ig = b_ih[jj]        + b_hh[jj];
        float fg = b_ih[512 + jj]  + b_hh[512 + jj];
        float gg = b_ih[1024 + jj] + b_hh[1024 + jj];
        float og = b_ih[1536 + jj] + b_hh[1536 + jj];
        #pragma unroll
        for (int s = 0; s < GSG; ++s) {
            const float* gp = gpart + ((size_t)s * 32 + b) * 2048;
            ig += gp[jj]; fg += gp[512 + jj]; gg += gp[1024 + jj]; og += gp[1536 + jj];
        }
        float si = 1.0f / (1.0f + expf(-ig));
        float sf = 1.0f / (1.0f + expf(-fg));
        float so = 1.0f / (1.0f + expf(-og));
        float cn = sf * c[b * 512 + jj] + si * tanhf(gg);
        float hn = so * tanhf(cn);
        c_s[jj] = cn; h_s[jj] = hn;
        c[b * 512 + jj] = cn;
    }
    __syncthreads();
    int nn = n_t[b * LL + it], tn = t_t[b * LL + it];   // inputs for step it+1
    for (int k = tid; k < 512; k += 256) {
        float hv = h_s[k], cv = c_s[k];
        hs[((size_t)b * LL + it) * 512 + k] = hv;
        xbuf[b * 1536 + k] = hv;
        xbuf[b * 1536 + 512 + k] = cv;
        xg[b * 1280 + 768 + k] = hv;
        xg[b * 1280 + 256 + k] = embT[(size_t)tn * 512 + k];
    }
    if (tid < 256) xg[b * 1280 + tid] = embN[(size_t)nn * 256 + tid];
    // s_t
    float acc = 0.0f;
    for (int k = tid; k < 512; k += 256) acc += h_s[k] * Ws_w[k];
    for (int k = tid; k < 512; k += 256) acc += c_s[k] * Ws_w[512 + k];
    red[tid] = acc;
    __syncthreads();
    for (int s2 = 128; s2 > 0; s2 >>= 1) {
        if (tid < s2) red[tid] += red[tid + s2];
        __syncthreads();
    }
    if (tid == 0) s_t[b] = 1.0f / (1.0f + expf(-(red[0] + Ws_b[0])));
}

// ---------------- big: blocks 0..31 Wh GEMM -> a; 32..271 logits GEMM -> lpart -
__global__ __launch_bounds__(256) void k_big(
        const float* __restrict__ Wg_w,
        const float* __restrict__ Wh_w, const float* __restrict__ Wh_b,
        const float* __restrict__ xbuf,
        float* __restrict__ lpart, float* __restrict__ a_out) {
    __shared__ float smem[32 * 512];   // 64 KB union
    int bx = blockIdx.x;
    int tid = threadIdx.x;
    if (bx < 32) {
        // ---- Wh part: a[b][j] = h[b] . Wh_w[j] + Wh_b[j], j-strip of 16
        float* h_s = smem;  // [32][512]
        for (int i = tid; i < 32 * 128; i += 256) {
            int b = i >> 7, f4 = i & 127;
            *(float4*)&h_s[b * 512 + f4 * 4] = *(const float4*)(xbuf + b * 1536 + f4 * 4);
        }
        __syncthreads();
        int j = bx * 16 + (tid & 15);
        int bg = tid >> 4;   // 0..15 -> b pair
        const float* wrow = Wh_w + (size_t)j * 512;
        const float* hp0 = h_s + (bg * 2) * 512;
        const float* hp1 = h_s + (bg * 2 + 1) * 512;
        float a0 = 0.f, a1 = 0.f;
        #pragma unroll 4
        for (int k = 0; k < 512; k += 4) {
            float4 w  = *(const float4*)(wrow + k);
            float4 x0 = *(const float4*)(hp0 + k);
            float4 x1 = *(const float4*)(hp1 + k);
            a0 += w.x*x0.x + w.y*x0.y + w.z*x0.z + w.w*x0.w;
            a1 += w.x*x1.x + w.y*x1.y + w.z*x1.z + w.w*x1.w;
        }
        float bias = Wh_b[j];
        a_out[(bg * 2) * 512 + j]     = a0 + bias;
        a_out[(bg * 2 + 1) * 512 + j] = a1 + bias;
    } else {
        // ---- logits GEMM: BN=256, BK=32, thread tile 4b x 8j
        float (*Ws)[256] = (float(*)[256])smem;             // [32][256]
        float (*Xs)[32]  = (float(*)[32])(smem + 32 * 256); // [32][32]
        int lb = bx - 32;
        int jb = lb % JBL, s = lb / JBL;
        int jt = jb * 256;
        int jq = tid & 31;          // j groups at jq*4 and 128+jq*4
        int bq = tid >> 5;          // b0 = bq*4
        int wjr = tid & 31, wkc = (tid >> 5) * 4;
        int xb  = tid & 31, xk  = (tid >> 5) * 4;
        float4 wreg[8], xreg;
        float acc[4][8];
        #pragma unroll
        for (int r = 0; r < 4; ++r)
            #pragma unroll
            for (int q = 0; q < 8; ++q) acc[r][q] = 0.f;
        const int kbase = s * 256;

        {   // prefetch chunk 0
            int k0 = kbase;
            #pragma unroll
            for (int r = 0; r < 8; ++r) {
                int row = jt + wjr + r * 32;
                if (row >= V_OUT) row = 0;
                wreg[r] = *(const float4*)(Wg_w + (size_t)row * 1536 + k0 + wkc);
            }
            xreg = *(const float4*)(xbuf + xb * 1536 + k0 + xk);
        }
        for (int ch = 0; ch < 8; ++ch) {
            __syncthreads();
            #pragma unroll
            for (int r = 0; r < 8; ++r) {
                Ws[wkc+0][wjr + r*32] = wreg[r].x;
                Ws[wkc+1][wjr + r*32] = wreg[r].y;
                Ws[wkc+2][wjr + r*32] = wreg[r].z;
                Ws[wkc+3][wjr + r*32] = wreg[r].w;
            }
            Xs[xk+0][xb] = xreg.x; Xs[xk+1][xb] = xreg.y;
            Xs[xk+2][xb] = xreg.z; Xs[xk+3][xb] = xreg.w;
            __syncthreads();
            if (ch < 7) {   // prefetch next chunk (overlaps compute)
                int k0 = kbase + (ch + 1) * 32;
                #pragma unroll
                for (int r = 0; r < 8; ++r) {
                    int row = jt + wjr + r * 32;
                    if (row >= V_OUT) row = 0;
                    wreg[r] = *(const float4*)(Wg_w + (size_t)row * 1536 + k0 + wkc);
                }
                xreg = *(const float4*)(xbuf + xb * 1536 + k0 + xk);
            }
            #pragma unroll 4
            for (int kk = 0; kk < 32; ++kk) {
                float4 xv = *(const float4*)&Xs[kk][bq * 4];
                float4 w0 = *(const float4*)&Ws[kk][jq * 4];
                float4 w1 = *(const float4*)&Ws[kk][128 + jq * 4];
                acc[0][0] += xv.x*w0.x; acc[0][1] += xv.x*w0.y; acc[0][2] += xv.x*w0.z; acc[0][3] += xv.x*w0.w;
                acc[0][4] += xv.x*w1.x; acc[0][5] += xv.x*w1.y; acc[0][6] += xv.x*w1.z; acc[0][7] += xv.x*w1.w;
                acc[1][0] += xv.y*w0.x; acc[1][1] += xv.y*w0.y; acc[1][2] += xv.y*w0.z; acc[1][3] += xv.y*w0.w;
                acc[1][4] += xv.y*w1.x; acc[1][5] += xv.y*w1.y; acc[1][6] += xv.y*w1.z; acc[1][7] += xv.y*w1.w;
                acc[2][0] += xv.z*w0.x; acc[2][1] += xv.z*w0.y; acc[2][2] += xv.z*w0.z; acc[2][3] += xv.z*w0.w;
                acc[2][4] += xv.z*w1.x; acc[2][5] += xv.z*w1.y; acc[2][6] += xv.z*w1.z; acc[2][7] += xv.z*w1.w;
                acc[3][0] += xv.w*w0.x; acc[3][1] += xv.w*w0.y; acc[3][2] += xv.w*w0.z; acc[3][3] += xv.w*w0.w;
                acc[3][4] += xv.w*w1.x; acc[3][5] += xv.w*w1.y; acc[3][6] += xv.w*w1.z; acc[3][7] += xv.w*w1.w;
            }
        }
        float* lp = lpart + (size_t)s * (BB * V_OUT);
        #pragma unroll
        for (int r = 0; r < 4; ++r) {
            float* dst = lp + (size_t)(bq * 4 + r) * V_OUT;
            #pragma unroll
            for (int q = 0; q < 4; ++q) {
                int j1 = jt + jq * 4 + q;
                if (j1 < V_OUT) dst[j1] = acc[r][q];
                int j2 = jt + 128 + jq * 4 + q;
                if (j2 < V_OUT) dst[j2] = acc[r][4 + q];
            }
        }
    }
}

// ---------------- per-b: scores+softmax (output-inert) + logit stats + loss ----
__global__ __launch_bounds__(256) void k_scorefinal(
        const float* __restrict__ lpart, const float* __restrict__ Wg_b,
        const float* __restrict__ a_out, const float* __restrict__ hs,
        const float* __restrict__ v_w, const float* __restrict__ v_b,
        const float* __restrict__ s_tp,
        const int* __restrict__ n_t, const int* __restrict__ t_t,
        float* __restrict__ tl_partial, float* __restrict__ out, int it) {
    __shared__ float a_s[512];
    __shared__ float sc[52];
    __shared__ float mv[256];
    __shared__ int   mi[256];
    __shared__ float sv[256];
    __shared__ float sh_vt, sh_ve;
    int b = blockIdx.x, tid = threadIdx.x;
    int lane = tid & 63, wv = tid >> 6;
    for (int k = tid; k < 512; k += 256) a_s[k] = a_out[b * 512 + k];
    __syncthreads();
    // scores (fast tanh: output-inert — only feeds the provably-false cond)
    for (int w = wv; w < ATTN; w += 4) {
        int idx = it + w - ATTN;
        int idxc = idx < 0 ? 0 : idx;
        bool mask = (idx < 0) || (n_t[b * LL + idxc] == EOF_N);
        float sres = -1e20f;
        if (!mask) {
            const float* mrow = hs + ((size_t)b * LL + idxc) * 512;
            float acc = 0.0f;
            for (int k = lane; k < 512; k += 64) {
                float x = a_s[k] + mrow[k];
                float e = __expf(2.0f * x);
                acc += v_w[k] * (1.0f - 2.0f / (e + 1.0f));
            }
            for (int o = 32; o > 0; o >>= 1) acc += __shfl_down(acc, o);
            sres = acc + v_b[0];
        }
        if (lane == 0) sc[w] = sres;
    }
    __syncthreads();
    if (tid == 0) {
        float m = -INFINITY;
        for (int w = 0; w < ATTN; w++) m = fmaxf(m, sc[w]);
        float Z = 0.0f, emax = 0.0f;
        for (int w = 0; w < ATTN; w++) {
            float e = __expf(sc[w] - m);
            Z += e;
            if (e > emax) emax = e;
        }
        sc[50] = emax / Z;   // amax of attn_w
        sc[51] = 1.0f;       // asum (softmax sums to 1; dead-branch only)
    }
    // pass 1: logits = Wg_b + sum of GSL split-K partials -> max/argmax/sum
    int t_col = t_t[b * LL + it];
    float lmax = -INFINITY; int limax = 0; float lsum = 0.0f;
    for (int j = tid; j < V_OUT; j += 256) {
        float v = Wg_b[j];
        #pragma unroll
        for (int s = 0; s < GSL; ++s)
            v += lpart[(size_t)s * (BB * V_OUT) + (size_t)b * V_OUT + j];
        lsum += v;
        if (v > lmax) { lmax = v; limax = j; }
        if (j == t_col) sh_vt = v;
        if (j == EOF_T) sh_ve = v;
    }
    mv[tid] = lmax; mi[tid] = limax; sv[tid] = lsum;
    __syncthreads();
    for (int s2 = 128; s2 > 0; s2 >>= 1) {
        if (tid < s2) {
            if (mv[tid + s2] > mv[tid] || (mv[tid + s2] == mv[tid] && mi[tid + s2] < mi[tid])) {
                mv[tid] = mv[tid + s2]; mi[tid] = mi[tid + s2];
            }
            sv[tid] += sv[tid + s2];
        }
        __syncthreads();
    }
    float M = mv[0]; int argJ = mi[0]; float sumL = sv[0];
    __syncthreads();
    // pass 2: esum
    float esum = 0.0f;
    for (int j = tid; j < V_OUT; j += 256) {
        float v = Wg_b[j];
        #pragma unroll
        for (int s = 0; s < GSL; ++s)
            v += lpart[(size_t)s * (BB * V_OUT) + (size_t)b * V_OUT + j];
        esum += expf(v - M);
    }
    sv[tid] = esum;
    __syncthreads();
    for (int s2 = 128; s2 > 0; s2 >>= 1) {
        if (tid < s2) sv[tid] += sv[tid + s2];
        __syncthreads();
    }
    if (tid == 0) {
        float lse = logf(sv[0]);
        float st = s_tp[b];
        float amax = sc[50], asum = sc[51];
        float max_out = st * (-lse);
        float max_loc = (1.0f - st) * amax;
        bool cond = max_out > max_loc;
        const float CONST_T = CONF * logf(CONF) + 0.1f * logf(SM_VAL);
        float tl; int topi;
        if (!cond) {
            topi = argJ;
            float off = M + lse;
            float out_t = st * (sh_vt - off);
            float out_e = st * (sh_ve - off);
            float S = st * (sumL - (float)V_OUT * off);
            tl = CONST_T - (SM_VAL * (S - out_e - out_t) + CONF * out_t);
        } else {
            topi = 0;  // pointer branch (provably unreachable; amax>0 would give VOCAB_T+aarg)
            float S = (1.0f - st) * asum;
            tl = CONST_T - SM_VAL * S;
        }
        if (t_col == EOF_T) tl = 0.0f;
        tl_partial[it * BB + b] = tl;
        out[1 + b * LL + it] = (float)topi;
    }
}

__global__ void k_sumloss(const float* __restrict__ tl_partial, float* __restrict__ out) {
    __shared__ float r[256];
    float a = 0.0f;
    for (int i = threadIdx.x; i < BB * LL; i += 256) a += tl_partial[i];
    r[threadIdx.x] = a;
    __syncthreads();
    for (int s = 128; s > 0; s >>= 1) {
        if (threadIdx.x < s) r[threadIdx.x] += r[threadIdx.x + s];
        __syncthreads();
    }
    if (threadIdx.x == 0) out[0] = r[0];
}

extern "C" void kernel_launch(void* const* d_in, const int* in_sizes, int n_in,
                              void* d_out, int out_size, void* d_ws, size_t ws_size,
                              hipStream_t stream) {
    const int*   n_t  = (const int*)d_in[0];
    const int*   t_t  = (const int*)d_in[1];
    const int*   p_t  = (const int*)d_in[2];
    const float* embN = (const float*)d_in[3];
    const float* embT = (const float*)d_in[4];
    const float* w_ih = (const float*)d_in[5];
    const float* w_hh = (const float*)d_in[6];
    const float* b_ih = (const float*)d_in[7];
    const float* b_hh = (const float*)d_in[8];
    const float* Wh_w = (const float*)d_in[9];
    const float* Wh_b = (const float*)d_in[10];
    const float* v_w  = (const float*)d_in[11];
    const float* v_b  = (const float*)d_in[12];
    const float* Wg_w = (const float*)d_in[13];
    const float* Wg_b = (const float*)d_in[14];
    const float* Ws_w = (const float*)d_in[15];
    const float* Ws_b = (const float*)d_in[16];
    float* out = (float*)d_out;

    // workspace layout (floats); gpart & lpart alias (disjoint lifetimes)
    float* ws = (float*)d_ws;
    float* hs         = ws;                   // 2,097,152
    float* c          = hs + 2097152;         // 16,384
    float* xbuf       = c + 16384;            // 32*1536 = 49,152  [h|c|hcp]
    float* xg         = xbuf + 49152;         // 32*1280 = 40,960  [embN|embT|h]
    float* a_out      = xg + 40960;           // 16,384
    float* s_t        = a_out + 16384;        // 32
    float* tl_partial = s_t + 32;             // 4,096
    float* gl         = tl_partial + 4096;    // max(GSG*32*2048, GSL*32*V_OUT) = 1,930,176
    // total = 4,154,336 floats = 16.62 MB

    k_init<<<2048, 256, 0, stream>>>(hs, c, xg, embN, embT);

    for (int it = 0; it < LL; ++it) {
        k_gates<<<dim3(32, GSG), 256, 0, stream>>>(w_ih, w_hh, xg, gl);
        k_cell<<<BB, 256, 0, stream>>>(gl, b_ih, b_hh, embN, embT, Ws_w, Ws_b,
                                       n_t, t_t, p_t, c, hs, xbuf, xg, s_t, it);
        k_big<<<32 + JBL * GSL, 256, 0, stream>>>(Wg_w, Wh_w, Wh_b, xbuf, gl, a_out);
        k_scorefinal<<<BB, 256, 0, stream>>>(gl, Wg_b, a_out, hs, v_w, v_b, s_t,
                                             n_t, t_t, tl_partial, out, it);
    }
    k_sumloss<<<1, 256, 0, stream>>>(tl_partial, out);
}